// Round 2
// baseline (53.440 us; speedup 1.0000x reference)
//
#include <hip/hip_runtime.h>
#include <hip/hip_bf16.h>

// SINDy: theta(N,969) @ (C*mask)(969,16), plus l1 = mean|C*mask|.
// N=262144, latent=16, lib = 1 + 16 + 136 + 816 = 969 (pad K to 992 = 31*32).
// Strategy: bf16 MFMA 16x16x32. Each wave handles 64 rows; each lane builds the
// full theta row (compile-time-indexed products from z kept in registers),
// stages bf16 chunks through swizzled wave-private LDS, reads back as A-frags.
// B-frags (coefficients) are pre-swizzled into d_ws by a prep kernel.

#define LIB    969
#define KPAD   992
#define NCHUNK 31
#define NROWS  262144
#define NOUT   16

typedef __attribute__((ext_vector_type(8))) short bf16x8;
typedef __attribute__((ext_vector_type(4))) float f32x4;

struct Tbl { unsigned char a[KPAD]; unsigned char b[KPAD]; unsigned char c[KPAD]; };
constexpr Tbl make_tbl() {
  Tbl t{}; int n = 0;
  // order must match reference: [1, z_i, z_i z_j (i<=j), z_i z_j z_k (i<=j<=k)]
  t.a[n] = 16; t.b[n] = 16; t.c[n] = 16; n++;                       // 1
  for (int i = 0; i < 16; i++) { t.a[n] = (unsigned char)i; t.b[n] = 16; t.c[n] = 16; n++; }
  for (int i = 0; i < 16; i++)
    for (int j = i; j < 16; j++) { t.a[n] = (unsigned char)i; t.b[n] = (unsigned char)j; t.c[n] = 16; n++; }
  for (int i = 0; i < 16; i++)
    for (int j = i; j < 16; j++)
      for (int k = j; k < 16; k++) { t.a[n] = (unsigned char)i; t.b[n] = (unsigned char)j; t.c[n] = (unsigned char)k; n++; }
  for (; n < KPAD; n++) { t.a[n] = 16; t.b[n] = 16; t.c[n] = 16; }  // pad (coeff rows are 0)
  return t;
}
constexpr Tbl TBL = make_tbl();

// manual fp32 -> bf16, round-to-nearest-even (trivially copyable types only)
__device__ inline unsigned short f2bf(float x) {
  unsigned int u = __builtin_bit_cast(unsigned int, x);
  u += 0x7fffu + ((u >> 16) & 1u);
  return (unsigned short)(u >> 16);
}
__device__ inline unsigned int pkbf(float a, float b) {
  unsigned int ua = __builtin_bit_cast(unsigned int, a);
  unsigned int ub = __builtin_bit_cast(unsigned int, b);
  ua += 0x7fffu + ((ua >> 16) & 1u);
  ub += 0x7fffu + ((ub >> 16) & 1u);
  return (ua >> 16) | (ub & 0xffff0000u);
}

// ---- prep: masked coeffs -> bf16 in B-fragment layout; L1 partial sums ----
// B-frag layout: lane l of the MFMA wants C[k = 8*(l>>4)+m][col = l&15] as 8
// contiguous bf16. Store element (t, o) with t = slice*32 + g*8 + m at
// ushort index ((slice*4 + g)*16 + o)*8 + m.
__global__ __launch_bounds__(256) void prep_kernel(const float* __restrict__ C,
                                                   const float* __restrict__ M,
                                                   unsigned short* __restrict__ Cb,
                                                   float* __restrict__ acc) {
  const int idx = blockIdx.x * 256 + threadIdx.x;   // 0 .. 15871 (= KPAD*16)
  const int t = idx >> 4, o = idx & 15;
  float v = 0.f;
  if (t < LIB) v = C[t * 16 + o] * M[t * 16 + o];
  const int slice = t >> 5, g = (t >> 3) & 3, m = t & 7;
  Cb[((slice * 4 + g) * 16 + o) * 8 + m] = f2bf(v);
  // L1: wave-reduce |v| then one atomic per wave
  float s = fabsf(v);
  #pragma unroll
  for (int off = 32; off > 0; off >>= 1) s += __shfl_down(s, off);
  if ((threadIdx.x & 63) == 0) atomicAdd(acc, s);
}

// swizzled byte offset of (row r, 16B-quad q) in a [64 rows][64 B] tile:
// every 8 consecutive rows cover all 8 16B-slots of a 128B bank span -> conflict-free
__device__ inline int swz(int r, int q) { return r * 64 + ((q ^ ((r >> 1) & 3)) << 4); }

__global__ __launch_bounds__(256) void sindy_kernel(const float* __restrict__ z,
                                                    const unsigned short* __restrict__ Cb,
                                                    const float* __restrict__ acc,
                                                    float* __restrict__ out) {
  __shared__ uint4 stage4[4][256];                    // 4 KB per wave, wave-private
  char* stage = (char*)&stage4[threadIdx.x >> 6][0];
  const int lane = threadIdx.x & 63;
  const int g = lane >> 4;                            // k-group for MFMA frags
  const int lr = lane & 15;                           // row-in-tile / col
  const int rowBase = blockIdx.x * 256 + (threadIdx.x >> 6) * 64;

  // lane's row of z, plus sentinel 1.0 at index 16
  float z17[17];
  {
    const float4* z4 = (const float4*)z;
    const int r = rowBase + lane;
    #pragma unroll
    for (int c4 = 0; c4 < 4; c4++) {
      float4 v = z4[r * 4 + c4];
      z17[c4 * 4 + 0] = v.x; z17[c4 * 4 + 1] = v.y;
      z17[c4 * 4 + 2] = v.z; z17[c4 * 4 + 3] = v.w;
    }
    z17[16] = 1.0f;
  }

  f32x4 acc4[4] = {{0.f,0.f,0.f,0.f},{0.f,0.f,0.f,0.f},{0.f,0.f,0.f,0.f},{0.f,0.f,0.f,0.f}};

  #pragma unroll
  for (int c = 0; c < NCHUNK; c++) {
    // build 32 library entries for this K-chunk (all indices compile-time)
    float th[32];
    #pragma unroll
    for (int m = 0; m < 32; m++) {
      const int t = c * 32 + m;
      th[m] = (z17[TBL.a[t]] * z17[TBL.b[t]]) * z17[TBL.c[t]];
    }
    unsigned int pk[16];
    #pragma unroll
    for (int m = 0; m < 16; m++) pk[m] = pkbf(th[2 * m], th[2 * m + 1]);
    // stage: lane = row, 4x ds_write_b128 (swizzled)
    #pragma unroll
    for (int q = 0; q < 4; q++)
      *(uint4*)(stage + swz(lane, q)) = make_uint4(pk[4*q], pk[4*q+1], pk[4*q+2], pk[4*q+3]);

    // B-frag: one coalesced 16B global read (L2-resident, 31 KB total)
    bf16x8 bfrag = *(const bf16x8*)(Cb + ((c * 4 + g) * 16 + lr) * 8);

    // 4 row-subtiles of 16: A-frag = row 16s+lr, k-quad g (swizzled), then MFMA
    #pragma unroll
    for (int s = 0; s < 4; s++) {
      const int r = 16 * s + lr;
      bf16x8 afrag = *(const bf16x8*)(stage + swz(r, g));
      acc4[s] = __builtin_amdgcn_mfma_f32_16x16x32_bf16(afrag, bfrag, acc4[s], 0, 0, 0);
    }
  }

  // C/D layout (m89-verified): col = lane&15, row = 4*(lane>>4) + reg
  #pragma unroll
  for (int s = 0; s < 4; s++) {
    #pragma unroll
    for (int p = 0; p < 4; p++)
      out[(rowBase + 16 * s + 4 * g + p) * 16 + lr] = acc4[s][p];
  }

  if (blockIdx.x == 0 && threadIdx.x == 0)
    out[NROWS * NOUT] = acc[0] * (1.0f / 15504.0f);   // mean over 969*16
}

extern "C" void kernel_launch(void* const* d_in, const int* in_sizes, int n_in,
                              void* d_out, int out_size, void* d_ws, size_t ws_size,
                              hipStream_t stream) {
  const float* z = (const float*)d_in[0];
  const float* C = (const float*)d_in[1];
  const float* M = (const float*)d_in[2];
  float* out = (float*)d_out;
  float* acc = (float*)d_ws;                          // [0]: L1 accumulator
  unsigned short* Cb = (unsigned short*)((char*)d_ws + 64); // 31744 B coeff tile

  (void)hipMemsetAsync(d_ws, 0, 4, stream);           // zero L1 accumulator
  prep_kernel<<<KPAD * 16 / 256, 256, 0, stream>>>(C, M, Cb, acc);
  sindy_kernel<<<NROWS / 256, 256, 0, stream>>>(z, Cb, acc, out);
}